// Round 4
// baseline (125.804 us; speedup 1.0000x reference)
//
#include <hip/hip_runtime.h>

// CanadarmJacob: 131072 independent items.
// R2 evidence: kernel <45.5us (absent from top-5; fillBuffer resets 45-47us
// dominate trace), dur_us=125 includes ~60-80us harness reset traffic.
// R3 change: LDS-stage com loads (coalesced float4 in) and output stores
// (coalesced float4 out) to cut per-instruction scattered-lane L2 requests.
// Pose remains direct float4 gather (touches 7/9 lines = fetch-optimal).

#define BLK 256

__global__ __launch_bounds__(BLK) void canadarm_jacob_kernel(
    const float* __restrict__ com,
    const float* __restrict__ pose,
    const int* __restrict__ bm_ptr,
    float* __restrict__ out,
    int n_items)
{
    // LDS shared between com staging (21504B) and out staging (43008B)
    __shared__ float lds[BLK * 42];   // 43008 B

    const int tid = threadIdx.x;
    const int idx = blockIdx.x * BLK + tid;   // n_items % BLK == 0 (131072/256)

    // ---- compile-time constants (match reference f32 values) ----
    const float MASS[7] = {105.98f, 105.98f, 314.98f, 279.2f, 105.98f, 105.98f, 243.66f};
    const float SUMM[7] = {1261.76f, 1155.78f, 1049.80f, 734.82f, 455.62f, 349.64f, 243.66f};
    const float SIX[7] = {79.083f, 66.893f, 54.703f, 39.293f, 29.771f, 21.466f, 9.336f};
    const float SIY[7] = {4144.971f, 4132.781f, 4120.591f, 2025.881f, 59.601f, 56.540f, 44.410f};
    const float SIZ[7] = {4131.1016f, 4128.0406f, 4124.9796f, 2021.7896f, 55.5096f, 47.471f, 44.410f};
    const float TM     = 101505.42f;
    const float INV_TM = 1.0f / 101505.42f;
    const float BCZ    = 6.65f * 243.66f / 100243.66f;

    // ---- stage com block into LDS, coalesced ----
    // block's com region: BLK*21 floats = 5376 floats = 1344 float4 (16B-aligned:
    // blockIdx*BLK*21*4 = blockIdx*21504, 21504%16==0)
    {
        const float4* Cb4 = reinterpret_cast<const float4*>(com) + (size_t)blockIdx.x * (BLK * 21 / 4);
        float4* L4 = reinterpret_cast<float4*>(lds);
#pragma unroll
        for (int i = 0; i < 5; ++i) L4[tid + i * BLK] = Cb4[tid + i * BLK];
        if (tid < BLK * 21 / 4 - 5 * BLK) L4[tid + 5 * BLK] = Cb4[tid + 5 * BLK];  // 1344-1280=64
    }
    __syncthreads();

    // ---- load pose: 7 aligned float4 per matrix row (direct gather) ----
    const float4* Pb = reinterpret_cast<const float4*>(pose) + (size_t)idx * 36;
    float rot[3][7];
    float tr[3][8];
#pragma unroll
    for (int r = 0; r < 3; ++r) {
        const float4 q0 = Pb[r * 9 + 0];
        const float4 q1 = Pb[r * 9 + 1];
        const float4 q4 = Pb[r * 9 + 4];
        const float4 q5 = Pb[r * 9 + 5];
        const float4 q6 = Pb[r * 9 + 6];
        const float4 q7 = Pb[r * 9 + 7];
        const float4 q8 = Pb[r * 9 + 8];
        rot[r][0] = q4.z;
        rot[r][1] = q0.y;
        rot[r][2] = q5.x;
        rot[r][3] = q5.y;
        rot[r][4] = -q5.z;   // ROT_SIGN[4] = -1
        rot[r][5] = q1.y;
        rot[r][6] = q6.x;
        tr[r][0] = q6.w;
        tr[r][1] = q7.x; tr[r][2] = q7.y; tr[r][3] = q7.z; tr[r][4] = q7.w;
        tr[r][5] = q8.x; tr[r][6] = q8.y; tr[r][7] = q8.z;
    }

    const int bm = bm_ptr[0];
    float o[42];

    if (bm) {
        // ---- read this thread's com from LDS (stride 21 floats: conflict-free) ----
        float cm[3][7];
#pragma unroll
        for (int r = 0; r < 3; ++r)
#pragma unroll
            for (int i = 0; i < 7; ++i) cm[r][i] = lds[tid * 21 + r * 7 + i];

        float scx = 0.f, scy = 0.f, scz = 0.f;
#pragma unroll
        for (int i = 0; i < 7; ++i) {
            scx += cm[0][i] * MASS[i];
            scy += cm[1][i] * MASS[i];
            scz += cm[2][i] * MASS[i];
        }
        const float vx = scx * INV_TM;
        const float vy = scy * INV_TM;
        const float vz = scz * INV_TM - BCZ;

        float dp[3][7], jt[3][7];
        float hxx = SIX[0], hyy = SIY[0], hzz = SIZ[0];
        float hxy = 0.f, hxz = 0.f, hyz = 0.f;
#pragma unroll
        for (int i = 0; i < 7; ++i) {
            const float x = cm[0][i] - tr[0][i];
            const float y = cm[1][i] - tr[1][i];
            const float z = cm[2][i] - tr[2][i];
            dp[0][i] = x; dp[1][i] = y; dp[2][i] = z;
            jt[0][i] = rot[1][i] * z - rot[2][i] * y;
            jt[1][i] = rot[2][i] * x - rot[0][i] * z;
            jt[2][i] = rot[0][i] * y - rot[1][i] * x;
            const float m = MASS[i];
            hxx += m * (y * y + z * z);
            hyy += m * (x * x + z * z);
            hzz += m * (x * x + y * y);
            hxy -= m * x * y;
            hxz -= m * x * z;
            hyz -= m * y * z;
        }

        float wx[7], wy[7], wz[7];
        wx[6] = MASS[6] * dp[0][6];
        wy[6] = MASS[6] * dp[1][6];
        wz[6] = MASS[6] * dp[2][6];
#pragma unroll
        for (int k = 5; k >= 0; --k) {
            wx[k] = wx[k + 1] + MASS[k] * dp[0][k];
            wy[k] = wy[k + 1] + MASS[k] * dp[1][k];
            wz[k] = wz[k + 1] + MASS[k] * dp[2][k];
        }

        const float vv = vx * vx + vy * vy + vz * vz;
        const float a  = hxx + TM * (vx * vx - vv);
        const float b  = hxy + TM * (vx * vy);
        const float c  = hxz + TM * (vx * vz);
        const float e  = hyy + TM * (vy * vy - vv);
        const float f  = hyz + TM * (vy * vz);
        const float i9 = hzz + TM * (vz * vz - vv);

        const float c11 = e * i9 - f * f;
        const float c12 = c * f - b * i9;
        const float c13 = b * f - e * c;
        const float det = a * c11 + b * c12 + c * c13;
        const float rdet = 1.0f / det;
        const float i00 = c11 * rdet;
        const float i01 = c12 * rdet;
        const float i02 = c13 * rdet;
        const float i11 = (a * i9 - c * c) * rdet;
        const float i12 = (c * b - a * f) * rdet;
        const float i22 = (a * e - b * b) * rdet;

#pragma unroll
        for (int k = 0; k < 7; ++k) {
            const float ux = wx[k] - SUMM[k] * vx;
            const float uy = wy[k] - SUMM[k] * vy;
            const float uz = wz[k] - SUMM[k] * vz;
            const float jx = jt[0][k], jy = jt[1][k], jz = jt[2][k];
            const float htx = SIX[k] * rot[0][k] + uy * jz - uz * jy;
            const float hty = SIY[k] * rot[1][k] + uz * jx - ux * jz;
            const float htz = SIZ[k] * rot[2][k] + ux * jy - uy * jx;
            const float bx = i00 * htx + i01 * hty + i02 * htz;
            const float by = i01 * htx + i11 * hty + i12 * htz;
            const float bz = i02 * htx + i12 * hty + i22 * htz;
            const float s = SUMM[k] * INV_TM;
            o[0 * 7 + k] = -(s * jx + vy * bz - vz * by);
            o[1 * 7 + k] = -(s * jy + vz * bx - vx * bz);
            o[2 * 7 + k] = -(s * jz + vx * by - vy * bx);
            o[3 * 7 + k] = -bx;
            o[4 * 7 + k] = -by;
            o[5 * 7 + k] = -bz;
        }
    } else {
#pragma unroll
        for (int k = 0; k < 7; ++k) {
            const float dx = tr[0][7] - tr[0][k];
            const float dy = tr[1][7] - tr[1][k];
            const float dz = tr[2][7] - tr[2][k];
            o[0 * 7 + k] = rot[1][k] * dz - rot[2][k] * dy;
            o[1 * 7 + k] = rot[2][k] * dx - rot[0][k] * dz;
            o[2 * 7 + k] = rot[0][k] * dy - rot[1][k] * dx;
            o[3 * 7 + k] = rot[0][k];
            o[4 * 7 + k] = rot[1][k];
            o[5 * 7 + k] = rot[2][k];
        }
    }

    // ---- stage output in LDS, then stream out coalesced as float4 ----
    __syncthreads();   // everyone done reading com from LDS
#pragma unroll
    for (int j = 0; j < 42; ++j) lds[tid * 42 + j] = o[j];   // stride 42: 2-way bank alias (free)
    __syncthreads();

    // block's out region: BLK*42 floats = 10752 = 2688 float4
    // (base byte = blockIdx*43008, 43008%16==0)
    {
        float4* Ob4 = reinterpret_cast<float4*>(out) + (size_t)blockIdx.x * (BLK * 42 / 4);
        const float4* L4 = reinterpret_cast<const float4*>(lds);
#pragma unroll
        for (int i = 0; i < 10; ++i) Ob4[tid + i * BLK] = L4[tid + i * BLK];
        if (tid < BLK * 42 / 4 - 10 * BLK) Ob4[tid + 10 * BLK] = L4[tid + 10 * BLK];  // 2688-2560=128
    }
}

extern "C" void kernel_launch(void* const* d_in, const int* in_sizes, int n_in,
                              void* d_out, int out_size, void* d_ws, size_t ws_size,
                              hipStream_t stream) {
    const float* com  = (const float*)d_in[0];   // (512,256,3,7)  f32
    const float* pose = (const float*)d_in[1];   // (512,256,4,4,9) f32
    const int*   bm   = (const int*)d_in[2];     // scalar
    float* out = (float*)d_out;                  // (512,256,6,7)  f32

    const int n_items = in_sizes[0] / 21;        // 131072 (divisible by BLK)
    const int grid = (n_items + BLK - 1) / BLK;  // 512
    canadarm_jacob_kernel<<<grid, BLK, 0, stream>>>(com, pose, bm, out, n_items);
}